// Round 1
// 595.557 us; speedup vs baseline: 1.1073x; 1.1073x over previous
//
#include <hip/hip_runtime.h>

#define M_OUT   125000
#define CIN     96
#define COUT    192
#define KOCT    8
#define MT      256      // rows per block: 8 waves x 32 rows
#define LDA     104      // padded bf16 stride for weights (96+8)
#define LDB     104
#define BN_EPS  1e-5f

// ws layout (floats at base):
//   [0,192)   sums   [192,384) sumsq   [384,576) scale   [576,768) shift
// byte 4096: bf16 WT[k][n][c_pad104]  (8*192*104*2 = 319488 B)
#define WS_SCALE_OFF 384
#define WS_WT_BYTE   4096

typedef __attribute__((ext_vector_type(8))) short bf16x8;
typedef __attribute__((ext_vector_type(4))) float f32x4;

__device__ __forceinline__ unsigned short f2bf(float f) {
    unsigned int u = __float_as_uint(f);
    u += 0x7FFF + ((u >> 16) & 1);           // RNE
    return (unsigned short)(u >> 16);
}

__device__ __forceinline__ unsigned int pack2(float a, float b) {
    unsigned int ua = __float_as_uint(a);
    unsigned int ub = __float_as_uint(b);
    ua += 0x7FFF + ((ua >> 16) & 1);
    ub += 0x7FFF + ((ub >> 16) & 1);
    return (ua >> 16) | (ub & 0xFFFF0000u);
}

__device__ __forceinline__ bf16x8 pack8(const float4 h0, const float4 h1) {
    union { unsigned int u[4]; bf16x8 v; } r;
    r.u[0] = pack2(h0.x, h0.y);
    r.u[1] = pack2(h0.z, h0.w);
    r.u[2] = pack2(h1.x, h1.y);
    r.u[3] = pack2(h1.z, h1.w);
    return r.v;
}

// select octant k's index out of two int4s (k constant after unroll -> folds)
__device__ __forceinline__ int sel8(const int4 a, const int4 b, int k) {
    switch (k & 7) {
        case 0: return a.x; case 1: return a.y; case 2: return a.z; case 3: return a.w;
        case 4: return b.x; case 5: return b.y; case 6: return b.z; default: return b.w;
    }
}

// ---------------- prep: zero stats + build bf16 transposed padded weights ----
__global__ void prep_kernel(const float* __restrict__ W, float* __restrict__ ws_f,
                            unsigned short* __restrict__ wt) {
    int gid = blockIdx.x * blockDim.x + threadIdx.x;
    if (gid < 384) ws_f[gid] = 0.0f;
    if (gid < KOCT * COUT * LDA) {
        int c = gid % LDA;
        int rest = gid / LDA;
        int n = rest % COUT;
        int k = rest / COUT;
        float v = (c < CIN) ? W[(k * CIN + c) * COUT + n] : 0.0f;
        wt[gid] = f2bf(v);
    }
}

// ---------------- conv: per-wave register gather-GEMM, 1-octant pipeline ----
// 512 threads = 8 waves. Wave w owns rows [m0 + 32w, m0 + 32w + 32), ALL 192 cols.
// A operand lives in registers only (gathered in MFMA fragment layout).
// B (weights) double-buffered in LDS via global_load_lds.
__global__ __launch_bounds__(512, 2)
void conv_kernel(const float* __restrict__ data,
                 const int* __restrict__ neigh,
                 const float* __restrict__ bias,
                 const unsigned short* __restrict__ wt,
                 float* __restrict__ out,
                 float* __restrict__ gsum) {
    __shared__ __align__(16) unsigned short Bs[2][COUT * LDB];  // 2 x 39936 B
    __shared__ float stats[2 * COUT];                           // 1536 B

    const int t    = threadIdx.x;
    const int wave = t >> 6;
    const int lane = t & 63;
    const int quad = lane >> 4;
    const int l15  = lane & 15;
    const int m0   = blockIdx.x * MT;

    for (int i = t; i < 2 * COUT; i += 512) stats[i] = 0.0f;

    // preload this lane's neighbor indices: 2 row-tiles x 8 octants (16 VGPRs)
    int4 nid[2][2];
#pragma unroll
    for (int rt = 0; rt < 2; ++rt) {
        int gm = m0 + wave * 32 + rt * 16 + l15;
        if (gm < M_OUT) {
            nid[rt][0] = *reinterpret_cast<const int4*>(neigh + (size_t)gm * 8);
            nid[rt][1] = *reinterpret_cast<const int4*>(neigh + (size_t)gm * 8 + 4);
        } else {
            nid[rt][0] = make_int4(-1, -1, -1, -1);
            nid[rt][1] = make_int4(-1, -1, -1, -1);
        }
    }

    f32x4 acc[2][12];
    const f32x4 vz = {0.f, 0.f, 0.f, 0.f};
#pragma unroll
    for (int i = 0; i < 2; ++i)
#pragma unroll
        for (int j = 0; j < 12; ++j) acc[i][j] = vz;

    float4 ar[12];          // raw fp32 gather (in flight across MFMA phase)
    bf16x8 af[2][2][3];     // packed A fragments, ping-pong by octant parity

    // issue octant k's gathers: lane reads 8 channels per (rt,ks) as 2 float4
    auto gather = [&](int k) {
#pragma unroll
        for (int rt = 0; rt < 2; ++rt) {
            int idx = sel8(nid[rt][0], nid[rt][1], k);
            const float* p = data + (size_t)idx * CIN + quad * 8;
#pragma unroll
            for (int ks = 0; ks < 3; ++ks)
#pragma unroll
                for (int h = 0; h < 2; ++h) {
                    float4 v = {0.f, 0.f, 0.f, 0.f};
                    if (idx >= 0) v = *reinterpret_cast<const float4*>(p + ks * 32 + h * 4);
                    ar[(rt * 3 + ks) * 2 + h] = v;
                }
        }
    };
    auto packA = [&](int buf) {
#pragma unroll
        for (int rt = 0; rt < 2; ++rt)
#pragma unroll
            for (int ks = 0; ks < 3; ++ks)
                af[buf][rt][ks] = pack8(ar[(rt * 3 + ks) * 2], ar[(rt * 3 + ks) * 2 + 1]);
    };
    // stage 39936 B of WT[k] into Bs[buf] as 39 wave-chunks of 1024 B
    auto stageB = [&](int k, int buf) {
        const char* src = (const char*)wt + (size_t)k * (COUT * LDB * 2);
        char* dst = (char*)&Bs[buf][0];
#pragma unroll
        for (int j = 0; j < 5; ++j) {
            int chunk = wave + 8 * j;
            if (chunk < 39) {
                __builtin_amdgcn_global_load_lds(
                    (const __attribute__((address_space(1))) unsigned int*)(src + chunk * 1024 + lane * 16),
                    (__attribute__((address_space(3))) unsigned int*)(dst + chunk * 1024 + lane * 16),
                    16, 0, 0);
            }
        }
    };
    auto mfmaPhase = [&](int kbuf, int bbuf) {
#pragma unroll
        for (int ks = 0; ks < 3; ++ks)
#pragma unroll
            for (int h = 0; h < 2; ++h) {     // two 96-col halves: caps bfr live-range
                bf16x8 bfr[6];
#pragma unroll
                for (int c = 0; c < 6; ++c) {
                    int n = h * 96 + c * 16 + l15;
                    bfr[c] = *reinterpret_cast<const bf16x8*>(&Bs[bbuf][n * LDB + ks * 32 + quad * 8]);
                }
#pragma unroll
                for (int rt = 0; rt < 2; ++rt)
#pragma unroll
                    for (int c = 0; c < 6; ++c)
                        acc[rt][h * 6 + c] = __builtin_amdgcn_mfma_f32_16x16x32_bf16(
                            af[kbuf][rt][ks], bfr[c], acc[rt][h * 6 + c], 0, 0, 0);
            }
    };

    // prologue: octant 0
    gather(0);
    stageB(0, 0);
    packA(0);
    __syncthreads();   // publishes Bs[0] (drains global_load_lds)

#pragma unroll
    for (int k = 0; k < KOCT; ++k) {
        const int cb = k & 1;
        if (k < KOCT - 1) {
            gather(k + 1);          // 12 scattered HBM loads -> regs (in flight)
            stageB(k + 1, cb ^ 1);  // 5 L2-hot global_load_lds (in flight)
        }
        __builtin_amdgcn_sched_barrier(0);   // keep issues before compute
        mfmaPhase(cb, cb);                   // ds_read B + 72 MFMA on current octant
        __builtin_amdgcn_sched_barrier(0);   // keep pack (and its vmcnt wait) after compute
        if (k < KOCT - 1) packA(cb ^ 1);     // compiler waits A loads (counted vmcnt)
        __syncthreads();                     // drains remaining B loads (long done)
    }

    // ---- epilogue: + bias, store conv-out fp32, per-channel sum/sumsq
#pragma unroll
    for (int ct = 0; ct < 12; ++ct) {
        int col = ct * 16 + l15;
        float b = bias[col];
        float s1 = 0.f, s2 = 0.f;
#pragma unroll
        for (int rt = 0; rt < 2; ++rt) {
#pragma unroll
            for (int r = 0; r < 4; ++r) {
                int gm = m0 + wave * 32 + rt * 16 + quad * 4 + r;
                if (gm < M_OUT) {
                    float v = acc[rt][ct][r] + b;
                    out[(size_t)gm * COUT + col] = v;
                    s1 += v;
                    s2 += v * v;
                }
            }
        }
        // reduce across the 4 quads (same col) before touching LDS
        s1 += __shfl_xor(s1, 16); s2 += __shfl_xor(s2, 16);
        s1 += __shfl_xor(s1, 32); s2 += __shfl_xor(s2, 32);
        if (quad == 0) {
            atomicAdd(&stats[col], s1);
            atomicAdd(&stats[COUT + col], s2);
        }
    }
    __syncthreads();
    for (int i = t; i < COUT; i += 512) {
        atomicAdd(&gsum[i], stats[i]);
        atomicAdd(&gsum[COUT + i], stats[COUT + i]);
    }
}

// ---------------- finalize: per-channel scale/shift -------------------------
__global__ void finalize_kernel(const float* __restrict__ gsum,
                                const float* __restrict__ gamma,
                                const float* __restrict__ beta,
                                float* __restrict__ ss) {
    int c = threadIdx.x;
    if (c < COUT) {
        float inv_m = 1.0f / (float)M_OUT;
        float mean = gsum[c] * inv_m;
        float var  = gsum[COUT + c] * inv_m - mean * mean;
        float rstd = rsqrtf(var + BN_EPS);
        float sc   = gamma[c] * rstd;
        ss[c]        = sc;
        ss[COUT + c] = beta[c] - mean * sc;
    }
}

// ---------------- normalize: y = x*scale[c] + shift[c] ----------------------
__global__ void norm_kernel(float* __restrict__ out, const float* __restrict__ ss) {
    __shared__ float s_scale[COUT], s_shift[COUT];
    for (int i = threadIdx.x; i < COUT; i += blockDim.x) {
        s_scale[i] = ss[i];
        s_shift[i] = ss[COUT + i];
    }
    __syncthreads();
    const int total4 = M_OUT * COUT / 4;   // 6,000,000
    int stride = gridDim.x * blockDim.x;
    for (int i = blockIdx.x * blockDim.x + threadIdx.x; i < total4; i += stride) {
        float4 v = reinterpret_cast<float4*>(out)[i];
        int c4 = (i % (COUT / 4)) * 4;
        v.x = v.x * s_scale[c4 + 0] + s_shift[c4 + 0];
        v.y = v.y * s_scale[c4 + 1] + s_shift[c4 + 1];
        v.z = v.z * s_scale[c4 + 2] + s_shift[c4 + 2];
        v.w = v.w * s_scale[c4 + 3] + s_shift[c4 + 3];
        reinterpret_cast<float4*>(out)[i] = v;
    }
}

extern "C" void kernel_launch(void* const* d_in, const int* in_sizes, int n_in,
                              void* d_out, int out_size, void* d_ws, size_t ws_size,
                              hipStream_t stream) {
    const float* data  = (const float*)d_in[0];
    const float* W     = (const float*)d_in[1];
    const float* bias  = (const float*)d_in[2];
    const float* gamma = (const float*)d_in[3];
    const float* beta  = (const float*)d_in[4];
    const int*   neigh = (const int*)d_in[5];
    float* out  = (float*)d_out;
    float* ws_f = (float*)d_ws;
    unsigned short* wt = (unsigned short*)((char*)d_ws + WS_WT_BYTE);

    // 1. prep: zero stats, build bf16 weights (8*192*104 = 159744 elems)
    prep_kernel<<<(KOCT * COUT * LDA + 255) / 256, 256, 0, stream>>>(W, ws_f, wt);

    // 2. gather-GEMM conv + stat accumulation (512 thr = 8 waves, 256 rows/blk)
    int grid1 = (M_OUT + MT - 1) / MT;   // 489
    conv_kernel<<<grid1, 512, 0, stream>>>(data, neigh, bias, wt, out, ws_f);

    // 3. per-channel scale/shift
    finalize_kernel<<<1, 192, 0, stream>>>(ws_f, gamma, beta, ws_f + WS_SCALE_OFF);

    // 4. in-place normalize
    norm_kernel<<<4096, 256, 0, stream>>>(out, ws_f + WS_SCALE_OFF);
}